// Round 2
// baseline (157.812 us; speedup 1.0000x reference)
//
#include <hip/hip_runtime.h>

// Batched 4096-point forward FFT (real input), 2048 rows.
// 4096 = 16 * 16 * 16: three radix-16 register stages, two LDS transposes.
// out[0 : B*N] = Re(FFT), out[B*N : 2*B*N] = Im(FFT), natural order.
//
// R3 post-mortem: Hermitian variant regressed (extra LDS RT + barriers).
// R4 post-mortem: LDS XOR-swizzle (kept below) was only -0.45us -> bank
// conflicts were NOT the critical path; they were hidden behind VMEM.
// R5 (this version): vectorize ALL global I/O to dwordx4. The old kernel
// issued 48 scalar dword VMEM instrs/thread (16 ld + 32 st) = ~25M VMEM
// instrs = ~41us of issue time at ~1 VMEM/cyc/CU -- matching the ~35us
// observed kernel time vs the 16us BW roofline. Now:
//   in : 4x global_load_dwordx4 -> LDS (linear b128) -> 16x ds_read_b32
//        stride-256 (conflict-free) for stage-A columns.
//   out: stage-C regs -> LDS split Re/Im float planes (b32, conflict-free)
//        -> 8x b128 read -> 8x global_store_dwordx4.
// VMEM instrs/thread 48 -> 12. +4 barriers, +64KB/block LDS traffic (LDS
// pipe has ~6x headroom). LDS stays 32KB -> __launch_bounds__(256,5)
// allows 5 blocks/CU (160KB exactly).

constexpr int NFFT  = 4096;
constexpr int BATCH = 2048;

struct cplx { float re, im; };
__device__ __forceinline__ cplx cmul(cplx a, cplx b){ return {a.re*b.re - a.im*b.im, a.re*b.im + a.im*b.re}; }
__device__ __forceinline__ cplx cadd(cplx a, cplx b){ return {a.re+b.re, a.im+b.im}; }
__device__ __forceinline__ cplx csub(cplx a, cplx b){ return {a.re-b.re, a.im-b.im}; }
__device__ __forceinline__ cplx cnegi(cplx a){ return { a.im, -a.re }; }   // a * (-i)

// forward radix-4: X[k] = sum_n z[n] (-i)^(nk), in-place over the 4 refs
__device__ __forceinline__ void dft4(cplx& a, cplx& b, cplx& c, cplx& d){
    cplx t0 = cadd(a,c), t1 = csub(a,c), t2 = cadd(b,d);
    cplx t3n = cnegi(csub(b,d));          // -i*(b-d)
    a = cadd(t0,t2);
    cplx nb = cadd(t1,t3n);
    c = csub(t0,t2);
    d = csub(t1,t3n);
    b = nb;
}

// RIDX[r] = 4*(r&3) + (r>>2): after dft16, output Y[r] sits in z[RIDX[r]]
__device__ __forceinline__ constexpr int RIDX(int r){ return 4*(r&3) + (r>>2); }

// in-place forward DFT-16 (digit-reversed output placement per RIDX)
__device__ __forceinline__ void dft16(cplx z[16]){
    dft4(z[0], z[4], z[8],  z[12]);
    dft4(z[1], z[5], z[9],  z[13]);
    dft4(z[2], z[6], z[10], z[14]);
    dft4(z[3], z[7], z[11], z[15]);
    constexpr float C1 = 0.92387953251128675613f;   // cos(pi/8)
    constexpr float S1 = 0.38268343236508977173f;   // sin(pi/8)
    constexpr float R2 = 0.70710678118654752440f;   // sqrt(2)/2
    z[5]  = cmul(z[5],  { C1,-S1});   // w16^1
    z[6]  = cmul(z[6],  { R2,-R2});   // w16^2
    z[7]  = cmul(z[7],  { S1,-C1});   // w16^3
    z[9]  = cmul(z[9],  { R2,-R2});   // w16^2
    z[10] = cnegi(z[10]);             // w16^4 = -i
    z[11] = cmul(z[11], {-R2,-R2});   // w16^6
    z[13] = cmul(z[13], { S1,-C1});   // w16^3
    z[14] = cmul(z[14], {-R2,-R2});   // w16^6
    z[15] = cmul(z[15], {-C1, S1});   // w16^9
    dft4(z[0],  z[1],  z[2],  z[3]);
    dft4(z[4],  z[5],  z[6],  z[7]);
    dft4(z[8],  z[9],  z[10], z[11]);
    dft4(z[12], z[13], z[14], z[15]);
}

// multiply output r (at z[RIDX(r)]) by w^r, w = e^{-2*pi*i*rev},
// using native v_sin/v_cos + logarithmic powering.
__device__ __forceinline__ void twiddle_all(cplx z[16], float rev){
    float ang = rev * 6.28318530717958647692f;
    float s = __sinf(ang), c = __cosf(ang);
    cplx w[16];
    w[0] = {1.0f, 0.0f};
    w[1] = {c, -s};
#pragma unroll
    for (int r = 2; r < 16; ++r) w[r] = cmul(w[r>>1], w[(r+1)>>1]);
#pragma unroll
    for (int r = 1; r < 16; ++r) z[RIDX(r)] = cmul(z[RIDX(r)], w[r]);
}

// Swizzled LDS float2 index: bank = 2*col' (row*32 drops out mod 32), col'
// mixes BOTH row nibbles so every access pattern's fast lane bits reach
// the bank index. All four float2 patterns land at 2 lanes/bank-pair (free).
__device__ __forceinline__ int sidx(int row, int col){
    return (row << 4) | (col ^ (((row >> 4) ^ row) & 15));
}

__global__ __launch_bounds__(256, 5)
void fft4096_r16(const float* __restrict__ x, float* __restrict__ out) {
    __shared__ float4 smem4[2048];           // 32768 B, aliased three ways
    float*  sf  = (float*)smem4;             // staging-in: float[4096]
    float2* su  = (float2*)smem4;            // stages A/B/C: float2[4096]
    float*  sre = (float*)smem4;             // staging-out Re: float[4096]
    float*  sim = sre + 4096;                // staging-out Im: float[4096]

    const int row = blockIdx.x;
    const int t   = threadIdx.x;             // 0..255
    const float* __restrict__ xr = x + (size_t)row * NFFT;

    cplx z[16];

    // ---- stage 0: vectorized load -> LDS staging (linear, conflict-free)
    {
        const float4* __restrict__ xv = (const float4*)xr;
        float4 xin[4];
#pragma unroll
        for (int j = 0; j < 4; ++j) xin[j] = xv[t + 256*j];
#pragma unroll
        for (int j = 0; j < 4; ++j) smem4[t + 256*j] = xin[j];
    }
    __syncthreads();

    // ---- stage A: thread t = n2. z[n1] = x[256*n1 + n2] from LDS,
    //      DFT16 over n1, twiddle w4096^(r*n2).
#pragma unroll
    for (int n1 = 0; n1 < 16; ++n1) z[n1] = { sf[n1*256 + t], 0.0f };
    dft16(z);
    twiddle_all(z, (float)t * (1.0f/4096.0f));
    __syncthreads();   // all sf reads done before su overwrite
#pragma unroll
    for (int r = 0; r < 16; ++r) su[sidx(t, r)] = { z[RIDX(r)].re, z[RIDX(r)].im };

    __syncthreads();

    // ---- stage B: thread (k1 = t>>4, m2 = t&15). z[m1] = u[k1][16*m1+m2],
    //      DFT16 over m1, twiddle w256^(k2*m2).
    {
        const int k1 = t >> 4, m2 = t & 15;
#pragma unroll
        for (int m1 = 0; m1 < 16; ++m1) {
            float2 v = su[sidx(16*m1 + m2, k1)];
            z[m1] = { v.x, v.y };
        }
        dft16(z);
        twiddle_all(z, (float)m2 * (1.0f/256.0f));
        __syncthreads();   // all reads of su done before overwrite
#pragma unroll
        for (int k2 = 0; k2 < 16; ++k2)
            su[sidx(k1*16 + k2, m2)] = { z[RIDX(k2)].re, z[RIDX(k2)].im };
    }

    __syncthreads();

    // ---- stage C: thread (k1 = t&15, k2 = t>>4). z[m2] = v[k1][k2][m2],
    //      DFT16 over m2 (no twiddle). X[t + 256*k3].
    {
        const int k1 = t & 15, k2 = t >> 4;
#pragma unroll
        for (int m2 = 0; m2 < 16; ++m2) {
            float2 v = su[sidx(k1*16 + k2, m2)];
            z[m2] = { v.x, v.y };
        }
        dft16(z);
    }
    __syncthreads();   // all su reads done before sre/sim overwrite

    // ---- stage D: regs -> LDS split planes -> vectorized global store.
    //      sre/sim writes at t+256*k3: lanes contiguous -> conflict-free.
#pragma unroll
    for (int k3 = 0; k3 < 16; ++k3) {
        sre[t + 256*k3] = z[RIDX(k3)].re;
        sim[t + 256*k3] = z[RIDX(k3)].im;
    }
    __syncthreads();

    {
        float4* __restrict__ oRe = (float4*)(out + (size_t)row * NFFT);
        float4* __restrict__ oIm = (float4*)(out + (size_t)BATCH * NFFT + (size_t)row * NFFT);
        const float4* sre4 = (const float4*)sre;
        const float4* sim4 = (const float4*)sim;
#pragma unroll
        for (int j = 0; j < 4; ++j) oRe[t + 256*j] = sre4[t + 256*j];
#pragma unroll
        for (int j = 0; j < 4; ++j) oIm[t + 256*j] = sim4[t + 256*j];
    }
}

extern "C" void kernel_launch(void* const* d_in, const int* in_sizes, int n_in,
                              void* d_out, int out_size, void* d_ws, size_t ws_size,
                              hipStream_t stream) {
    (void)in_sizes; (void)n_in; (void)d_ws; (void)ws_size; (void)out_size;
    const float* x = (const float*)d_in[0];   // (2048, 4096) fp32
    float* out = (float*)d_out;               // re plane then im plane
    fft4096_r16<<<dim3(BATCH), dim3(256), 0, stream>>>(x, out);
}

// Round 3
// 133.199 us; speedup vs baseline: 1.1848x; 1.1848x over previous
//
#include <hip/hip_runtime.h>

// Batched 4096-point forward FFT (real input), 2048 rows.
// 4096 = 16 * 16 * 16: three radix-16 register stages, two LDS transposes.
// out[0 : B*N] = Re(FFT), out[B*N : 2*B*N] = Im(FFT), natural order.
//
// R3 post-mortem: Hermitian variant regressed (extra LDS RT + barriers).
// R4 post-mortem: LDS XOR-swizzle kept (neutral-to-slightly-positive);
//   bank conflicts were not the critical path.
// R5 post-mortem: vectorizing global I/O via LDS staging REGRESSED
//   132 -> 158us (kernel 23.5 -> 49us). Scalar dword I/O was already
//   issue-parallel across SIMDs and latency-hidden; the staging barriers
//   destroyed load/compute/store streaming overlap. REVERTED.
// Envelope accounting (R5 counters): kernel pays a ~52MiB Infinity-Cache
//   eviction tax from the harness poison fills; effective kernel floor
//   ~24.5us == what this form already achieves. Remaining headroom <1us.

constexpr int NFFT  = 4096;
constexpr int BATCH = 2048;

struct cplx { float re, im; };
__device__ __forceinline__ cplx cmul(cplx a, cplx b){ return {a.re*b.re - a.im*b.im, a.re*b.im + a.im*b.re}; }
__device__ __forceinline__ cplx cadd(cplx a, cplx b){ return {a.re+b.re, a.im+b.im}; }
__device__ __forceinline__ cplx csub(cplx a, cplx b){ return {a.re-b.re, a.im-b.im}; }
__device__ __forceinline__ cplx cnegi(cplx a){ return { a.im, -a.re }; }   // a * (-i)

// forward radix-4: X[k] = sum_n z[n] (-i)^(nk), in-place over the 4 refs
__device__ __forceinline__ void dft4(cplx& a, cplx& b, cplx& c, cplx& d){
    cplx t0 = cadd(a,c), t1 = csub(a,c), t2 = cadd(b,d);
    cplx t3n = cnegi(csub(b,d));          // -i*(b-d)
    a = cadd(t0,t2);
    cplx nb = cadd(t1,t3n);
    c = csub(t0,t2);
    d = csub(t1,t3n);
    b = nb;
}

// RIDX[r] = 4*(r&3) + (r>>2): after dft16, output Y[r] sits in z[RIDX[r]]
__device__ __forceinline__ constexpr int RIDX(int r){ return 4*(r&3) + (r>>2); }

// in-place forward DFT-16 (digit-reversed output placement per RIDX)
__device__ __forceinline__ void dft16(cplx z[16]){
    dft4(z[0], z[4], z[8],  z[12]);
    dft4(z[1], z[5], z[9],  z[13]);
    dft4(z[2], z[6], z[10], z[14]);
    dft4(z[3], z[7], z[11], z[15]);
    constexpr float C1 = 0.92387953251128675613f;   // cos(pi/8)
    constexpr float S1 = 0.38268343236508977173f;   // sin(pi/8)
    constexpr float R2 = 0.70710678118654752440f;   // sqrt(2)/2
    z[5]  = cmul(z[5],  { C1,-S1});   // w16^1
    z[6]  = cmul(z[6],  { R2,-R2});   // w16^2
    z[7]  = cmul(z[7],  { S1,-C1});   // w16^3
    z[9]  = cmul(z[9],  { R2,-R2});   // w16^2
    z[10] = cnegi(z[10]);             // w16^4 = -i
    z[11] = cmul(z[11], {-R2,-R2});   // w16^6
    z[13] = cmul(z[13], { S1,-C1});   // w16^3
    z[14] = cmul(z[14], {-R2,-R2});   // w16^6
    z[15] = cmul(z[15], {-C1, S1});   // w16^9
    dft4(z[0],  z[1],  z[2],  z[3]);
    dft4(z[4],  z[5],  z[6],  z[7]);
    dft4(z[8],  z[9],  z[10], z[11]);
    dft4(z[12], z[13], z[14], z[15]);
}

// multiply output r (at z[RIDX(r)]) by w^r, w = e^{-2*pi*i*rev},
// using native v_sin/v_cos + logarithmic powering.
__device__ __forceinline__ void twiddle_all(cplx z[16], float rev){
    float ang = rev * 6.28318530717958647692f;
    float s = __sinf(ang), c = __cosf(ang);
    cplx w[16];
    w[0] = {1.0f, 0.0f};
    w[1] = {c, -s};
#pragma unroll
    for (int r = 2; r < 16; ++r) w[r] = cmul(w[r>>1], w[(r+1)>>1]);
#pragma unroll
    for (int r = 1; r < 16; ++r) z[RIDX(r)] = cmul(z[RIDX(r)], w[r]);
}

// Swizzled LDS index: bank = 2*col' (row*32 drops out mod 32), and col'
// mixes BOTH row nibbles so every access pattern's fast lane bits reach
// the bank index. All four patterns land at 2 lanes/bank-pair (free).
__device__ __forceinline__ int sidx(int row, int col){
    return (row << 4) | (col ^ (((row >> 4) ^ row) & 15));
}

__global__ __launch_bounds__(256, 4)
void fft4096_r16(const float* __restrict__ x, float* __restrict__ out) {
    __shared__ float2 su[256 * 16];          // 32768 B

    const int row = blockIdx.x;
    const int t   = threadIdx.x;             // 0..255
    const float* __restrict__ xr = x + (size_t)row * NFFT;

    cplx z[16];

    // ---- stage A: thread t = n2. z[n1] = x[256*n1 + n2], DFT16 over n1,
    //      twiddle w4096^(r*n2).
#pragma unroll
    for (int n1 = 0; n1 < 16; ++n1) z[n1] = { xr[n1*256 + t], 0.0f };
    dft16(z);
    twiddle_all(z, (float)t * (1.0f/4096.0f));
#pragma unroll
    for (int r = 0; r < 16; ++r) su[sidx(t, r)] = { z[RIDX(r)].re, z[RIDX(r)].im };

    __syncthreads();

    // ---- stage B: thread (k1 = t>>4, m2 = t&15). z[m1] = u[k1][16*m1+m2],
    //      DFT16 over m1, twiddle w256^(k2*m2).
    {
        const int k1 = t >> 4, m2 = t & 15;
#pragma unroll
        for (int m1 = 0; m1 < 16; ++m1) {
            float2 v = su[sidx(16*m1 + m2, k1)];
            z[m1] = { v.x, v.y };
        }
        dft16(z);
        twiddle_all(z, (float)m2 * (1.0f/256.0f));
        __syncthreads();   // all reads of su done before overwrite
#pragma unroll
        for (int k2 = 0; k2 < 16; ++k2)
            su[sidx(k1*16 + k2, m2)] = { z[RIDX(k2)].re, z[RIDX(k2)].im };
    }

    __syncthreads();

    // ---- stage C: thread (k1 = t&15, k2 = t>>4). z[m2] = v[k1][k2][m2],
    //      DFT16 over m2 (no twiddle). X[t + 256*k3].
    {
        const int k1 = t & 15, k2 = t >> 4;
#pragma unroll
        for (int m2 = 0; m2 < 16; ++m2) {
            float2 v = su[sidx(k1*16 + k2, m2)];
            z[m2] = { v.x, v.y };
        }
        dft16(z);
        float* __restrict__ outRe = out + (size_t)row * NFFT;
        float* __restrict__ outIm = out + (size_t)BATCH * NFFT + (size_t)row * NFFT;
#pragma unroll
        for (int k3 = 0; k3 < 16; ++k3) {
            outRe[t + 256*k3] = z[RIDX(k3)].re;
            outIm[t + 256*k3] = z[RIDX(k3)].im;
        }
    }
}

extern "C" void kernel_launch(void* const* d_in, const int* in_sizes, int n_in,
                              void* d_out, int out_size, void* d_ws, size_t ws_size,
                              hipStream_t stream) {
    (void)in_sizes; (void)n_in; (void)d_ws; (void)ws_size; (void)out_size;
    const float* x = (const float*)d_in[0];   // (2048, 4096) fp32
    float* out = (float*)d_out;               // re plane then im plane
    fft4096_r16<<<dim3(BATCH), dim3(256), 0, stream>>>(x, out);
}